// Round 9
// baseline (3943.104 us; speedup 1.0000x reference)
//
#include <hip/hip_runtime.h>

typedef __attribute__((ext_vector_type(8))) short bf16x8;
typedef __attribute__((ext_vector_type(4))) float f32x4;
typedef __attribute__((ext_vector_type(4))) int i32x4;

#define Tn 1024
#define Bn 64
#define Hn 2048
#define NBLK 256
#define NTHR 512

// R16 geometry (PROVEN): TWO independent rings (batch rows never mix in a
// GRU). Ring R owns batch rows [32R, 32R+32); 128 col-blocks of 16 cols per
// ring. blockIdx.x -> R = bid & 1, c = bid >> 1.
//
// REGISTER WALL (R18): 8-wave blocks -> 256 unified regs/wave. 16 cols ✓.
//
// Dataflow ready counters: one line per (ring, consumer-leaf, K-slice-group).
// 2 rings x 16 leaves x 8 groups = 256 counters, each on its own 128B line
// (32 KB ctrl). Replica (R, leaf, g) is bumped once per step by the CLOSER
// wave of each of the 16 producer col-blocks of group g in ring R (c>>4==g);
// value == 16*(t+1) means ring R's h_{t+1} slice g is fully at MALL.
// Consumers: wave w of col-block c polls (R, c>>3, w) -> 8 pollers/line.
#define GRP(ring, leaf, g) (((((ring) << 7) | ((leaf) << 3) | (g))) * 32)

// watchdog: bounded spin so a liveness bug degrades to a wrong answer
// (diagnosable absmax failure) instead of a container-killing hang
#define SPIN_LIMIT (1u << 25)

__device__ __forceinline__ unsigned short f2b(float x) {
    // fp32 -> bf16 round-to-nearest-even
    unsigned u = __float_as_uint(x);
    return (unsigned short)((u + 0x7fffu + ((u >> 16) & 1u)) >> 16);
}
__device__ __forceinline__ float sigm(float x) {
    return __builtin_amdgcn_rcpf(1.0f + __expf(-x));
}
__device__ __forceinline__ float tanh_f(float x) {
    float e = __expf(2.0f * x);
    return 1.0f - 2.0f * __builtin_amdgcn_rcpf(1.0f + e);
}

// write-through system-scope stores: at MALL once vmcnt retires
__device__ __forceinline__ void store_short_wt(unsigned short* p, unsigned v) {
    asm volatile("global_store_short %0, %1, off sc0 sc1" :: "v"(p), "v"(v) : "memory");
}
__device__ __forceinline__ void store_dword_wt(float* p, float v) {
    asm volatile("global_store_dword %0, %1, off sc0 sc1" :: "v"(p), "v"(__float_as_uint(v)) : "memory");
}
__device__ __forceinline__ void store_u64_wt(unsigned long long* p, unsigned long long v) {
    asm volatile("global_store_dwordx2 %0, %1, off sc0 sc1" :: "v"(p), "v"(v) : "memory");
}

// h fragment layout (GLOBAL, shared by both rings; each ring touches only its
// own mt stripes): h_f[kk][mt][laneF][e], kk=k>>5, mt=b>>4,
// laneF=((k>>3)&3)*16+(b&15), e=k&7. One MFMA A-frag = 64 lanes x 16B contig.
__device__ __forceinline__ long hfrag_off(int b, int k) {
    return ((long)(((k >> 5) * 4 + (b >> 4)) * 64) + ((k >> 3) & 3) * 16 + (b & 15)) * 8 + (k & 7);
}

// Prep: init_hidden fp32 -> bf16 h0 (frag layout, WT stores so the MALL copy
// is authoritative for gru's bypass loads); zero ready counters (WT too).
__global__ void prep_kernel(const float* __restrict__ init_h,
                            unsigned short* __restrict__ h0,
                            unsigned* __restrict__ ctrl) {
    const int i = blockIdx.x * 256 + threadIdx.x;  // 0..32767
    const int b  = i >> 9;
    const int k4 = (i & 511) << 2;
    float4 v = *reinterpret_cast<const float4*>(init_h + (long)b * Hn + k4);
    unsigned long long q = (unsigned long long)f2b(v.x)
                         | ((unsigned long long)f2b(v.y) << 16)
                         | ((unsigned long long)f2b(v.z) << 32)
                         | ((unsigned long long)f2b(v.w) << 48);
    store_u64_wt((unsigned long long*)(h0 + hfrag_off(b, k4)), q);
    if (i < 8192)
        asm volatile("global_store_dword %0, %1, off sc0 sc1"
                     :: "v"(ctrl + i), "v"(0u) : "memory");
}

// Persistent GRU. 256 blocks x 512 threads (8 waves) = 1 block/CU, all CUs.
// Ring R (bid&1) owns batch rows [32R,32R+32); col-block c (bid>>1) owns 16
// hidden units j in [16c, 16c+16). Wave w owns K-slice [256w, 256w+256);
// W rows live in REGISTERS (Bf[3][8] = 96 VGPRs).
//
// Ledger: R13 dataflow flags (-11%). R14 REVERTED (x loads stay BEFORE the
//   poll; LDS ops stay BATCHED). R15 setprio null (kept). R16 2-ring split +
//   single 16-load burst (-23%, 4337). R17 null -> reverted. R18 32-col:
//   register wall, REVERTED. R19 counted-vmcnt 2-way (-5%, 4115). R20 4-way
//   vmcnt ladder + single-round reduce (-7%, 3836).
// R21 (this): protocol trims at both ends.
//   (1) SPREAD EPILOGUE: 512 output elements = 8 waves x 64 lanes exactly;
//       each lane owns ONE (row,col): erow=4w+(lane>>4), ecol=lane&15.
//       Bucket-sum = 24 scalar ds_read_b32/lane (conflict-free: 64 lanes
//       span 256 contiguous bytes per plane); gate math 4x->1x per lane.
//       Same ascending src 0..7 sum order -> BITWISE-IDENTICAL results.
//   (2) CLOSER BUMP: each wave drains its OWN stores (vmcnt0) then bumps an
//       LDS counter; the 8th wave fires the 16-replica ctrl bump at once.
//       sync4 (red[] WAR fence) moves AFTER the bump -> off the ring path.
//       Invariant preserved: closer-bump => all 8 waves' vmcnt(0)-after-
//       stores done => block's h_{t+1} fully at MALL; and every wave's Q3
//       vmcnt(0) precedes its LDS-atomic => h_t reads complete before
//       bump(t) => R13 buffer-reuse induction carries verbatim.
//   (3) 2-DEEP PIPELINED POLL: two outstanding RMW slots alternated with
//       vmcnt(1) -> counter sampled every ~RTT/2 instead of every RTT.
//       The <=1 leftover poll op is OLDER than all h loads, so the ladder
//       constants still guarantee hb[0..3/7/11/15] retired (oldest-first
//       retirement, m135; same argument as the 3 pre-poll x loads).
//
// NO fences / cache maintenance in the hot loop (R5). All signals via RMW,
// all polls via RMW(+0).
__global__ void __launch_bounds__(NTHR, 2) gru_kernel(
    const float* __restrict__ inp,     // [T][B][3]
    const float* __restrict__ init_h,  // [B][H]
    const float* __restrict__ w_ih,    // [3H][3]
    const float* __restrict__ w_hh,    // [3H][H] fp32
    const float* __restrict__ bias,    // [3H]
    const float* __restrict__ bias_n,  // [H]
    unsigned short* __restrict__ h0,   // [B][H] bf16 frag-layout double buffer
    unsigned short* __restrict__ h1,
    unsigned* __restrict__ ctrl,       // [8192] ready counters (256 lines)
    float* __restrict__ out)           // [T][B]
{
    __shared__ f32x4 red[8][2][3][64];  // [bucket][m][gate][lane] = 48 KB
    __shared__ unsigned lcnt;           // closer counter (monotonic, 8/step)

    const int tid  = threadIdx.x;
    const int lane = tid & 63;
    const int w    = tid >> 6;      // wave id = K-slice owner
    const int quad = lane >> 4;
    const int n16  = lane & 15;
    const int R    = blockIdx.x & 1;        // ring id (batch half)
    const int c    = blockIdx.x >> 1;       // col-block id 0..127
    const int ks   = w * 256;
    const int bbase = 32 * R;       // ring's batch base

    // ---- preload W rows into registers as bf16 B-fragments (one-time) ----
    bf16x8 Bf[3][8];
    #pragma unroll
    for (int nt = 0; nt < 3; ++nt) {
        const long row = (long)(nt * Hn + c * 16 + n16);
        #pragma unroll
        for (int k = 0; k < 8; ++k) {
            const float* p = w_hh + row * Hn + ks + k * 32 + quad * 8;
            bf16x8 b;
            #pragma unroll
            for (int j = 0; j < 8; ++j) b[j] = (short)f2b(p[j]);
            Bf[nt][k] = b;
        }
    }

    // ---- spread-epilogue element mapping: one (row,col) per lane ----
    const int erow = 4 * w + quad;      // ring-row 0..31
    const int ecol = n16;               // col-within-block 0..15
    const int mE   = w >> 2;            // erow>>4 (bucket m stripe)
    const int rE   = quad;              // erow&3 (f32x4 component)
    const int jgE  = c * 16 + ecol;     // global hidden column
    // scalar offset into a (src,m,gate) plane of red (as float[256])
    const int eoff = ((w & 3) * 16 + ecol) * 4 + rE;

    // Epilogue constants (ALL waves; one element per lane)
    float wr0 = w_ih[jgE*3+0], wr1 = w_ih[jgE*3+1], wr2 = w_ih[jgE*3+2];
    float wz0 = w_ih[(Hn+jgE)*3+0], wz1 = w_ih[(Hn+jgE)*3+1], wz2 = w_ih[(Hn+jgE)*3+2];
    float wn0 = w_ih[(2*Hn+jgE)*3+0], wn1 = w_ih[(2*Hn+jgE)*3+1], wn2 = w_ih[(2*Hn+jgE)*3+2];
    float br_ = bias[jgE], bz_ = bias[Hn+jgE], bn2_ = bias[2*Hn+jgE];
    float bnn_ = bias_n[jgE];

    // fp32 hidden state: one element per lane
    float hst = init_h[(long)(bbase + erow) * Hn + jgE];

    // epilogue frag-store decomposition of j = 16c + ecol (mt = 2R + mE)
    const int kkE = c >> 1;
    const int qE  = (c & 1) * 2 + (ecol >> 3);
    const int eEc = ecol & 7;

    const int leafC = c >> 3;          // consumer replica index (per ring)
    const int grp   = c >> 4;          // K-slice group we produce (per ring)

    if (tid == 0) lcnt = 0u;
    __syncthreads();   // lcnt visible to all waves before the loop

    for (int t = 0; t < Tn; ++t) {
        const unsigned short* hcur = (t & 1) ? h1 : h0;
        unsigned short* hnext      = (t & 1) ? h0 : h1;

        // per-lane x inputs for this step's element. Issued BEFORE the poll:
        // their RTT hides under the poll's own RMW RTT (R14 lesson).
        float xv0, xv1, xv2;
        {
            const float* xp = inp + ((long)t * Bn + bbase + erow) * 3;
            xv0 = xp[0]; xv1 = xp[1]; xv2 = xp[2];
        }

        f32x4 acc[2][3];
        #pragma unroll
        for (int m = 0; m < 2; ++m)
            #pragma unroll
            for (int nt = 0; nt < 3; ++nt)
                acc[m][nt] = f32x4{0.f, 0.f, 0.f, 0.f};

        // ---- 2-deep pipelined dataflow wait (R21): two outstanding RMW
        // slots, alternated with vmcnt(1) -> counter sampled ~every RTT/2.
        // On exit <=1 poll op may remain outstanding (OLDER than the h
        // loads -> absorbed by the ladder constants below).
        if (lane == 0 && t) {
            const unsigned tgt = (unsigned)(t << 4);   // 16*t
            unsigned* p = &ctrl[GRP(R, leafC, w)];
            unsigned va, vb, spins = 0;
            asm volatile("global_atomic_add %0, %1, %2, off sc0 sc1"
                         : "=v"(va) : "v"(p), "v"(0u) : "memory");
            asm volatile("global_atomic_add %0, %1, %2, off sc0 sc1"
                         : "=v"(vb) : "v"(p), "v"(0u) : "memory");
            for (;;) {
                asm volatile("s_waitcnt vmcnt(1)" : "+v"(va) :: "memory");
                if (va >= tgt) break;
                __builtin_amdgcn_s_sleep(1);
                if (++spins > SPIN_LIMIT) break;   // watchdog
                asm volatile("global_atomic_add %0, %1, %2, off sc0 sc1"
                             : "=v"(va) : "v"(p), "v"(0u) : "memory");
                asm volatile("s_waitcnt vmcnt(1)" : "+v"(vb) :: "memory");
                if (vb >= tgt) break;
                __builtin_amdgcn_s_sleep(1);
                if (++spins > SPIN_LIMIT) break;   // watchdog
                asm volatile("global_atomic_add %0, %1, %2, off sc0 sc1"
                             : "=v"(vb) : "v"(p), "v"(0u) : "memory");
            }
        }

        // wave's A-frag base: frag f = 32w + 4*kki + 2R + m, at short-offset
        // f*512 + lane*8 (this ring's two mt stripes of the wave's kk range)
        const unsigned short* pa = hcur + ((long)(32 * w + 2 * R) * 64 + lane) * 8;

        // ---- ONE 16-load burst, 4-way counted-vmcnt ladder (R20) ----
        // Ladder safety with <=4 older outstanding ops (3 x loads + <=1 poll
        // slot): vmcnt(N) forces >= (older+16-N) retirements, oldest-first,
        // so each quarter's hb regs are retired exactly as in R20.
        i32x4 hb[16];
        #pragma unroll
        for (int kki = 0; kki < 8; ++kki) {
            #pragma unroll
            for (int m = 0; m < 2; ++m) {
                asm volatile("global_load_dwordx4 %0, %1, off sc0 sc1"
                             : "=v"(hb[kki * 2 + m])
                             : "v"(pa + (long)(kki * 4 + m) * 512) : "memory");
            }
        }
        asm volatile("s_waitcnt vmcnt(12)"
                     : "+v"(hb[0]), "+v"(hb[1]), "+v"(hb[2]), "+v"(hb[3])
                     :: "memory");
        __builtin_amdgcn_s_setprio(1);
        #pragma unroll
        for (int kki = 0; kki < 2; ++kki) {
            #pragma unroll
            for (int m = 0; m < 2; ++m) {
                union { i32x4 q; bf16x8 v; } u;
                u.q = hb[kki * 2 + m];
                bf16x8 a = u.v;
                acc[m][0] = __builtin_amdgcn_mfma_f32_16x16x32_bf16(a, Bf[0][kki], acc[m][0], 0, 0, 0);
                acc[m][1] = __builtin_amdgcn_mfma_f32_16x16x32_bf16(a, Bf[1][kki], acc[m][1], 0, 0, 0);
                acc[m][2] = __builtin_amdgcn_mfma_f32_16x16x32_bf16(a, Bf[2][kki], acc[m][2], 0, 0, 0);
            }
        }
        __builtin_amdgcn_s_setprio(0);
        asm volatile("s_waitcnt vmcnt(8)"
                     : "+v"(hb[4]), "+v"(hb[5]), "+v"(hb[6]), "+v"(hb[7])
                     :: "memory");
        __builtin_amdgcn_s_setprio(1);
        #pragma unroll
        for (int kki = 2; kki < 4; ++kki) {
            #pragma unroll
            for (int m = 0; m < 2; ++m) {
                union { i32x4 q; bf16x8 v; } u;
                u.q = hb[kki * 2 + m];
                bf16x8 a = u.v;
                acc[m][0] = __builtin_amdgcn_mfma_f32_16x16x32_bf16(a, Bf[0][kki], acc[m][0], 0, 0, 0);
                acc[m][1] = __builtin_amdgcn_mfma_f32_16x16x32_bf16(a, Bf[1][kki], acc[m][1], 0, 0, 0);
                acc[m][2] = __builtin_amdgcn_mfma_f32_16x16x32_bf16(a, Bf[2][kki], acc[m][2], 0, 0, 0);
            }
        }
        __builtin_amdgcn_s_setprio(0);
        asm volatile("s_waitcnt vmcnt(4)"
                     : "+v"(hb[8]), "+v"(hb[9]), "+v"(hb[10]), "+v"(hb[11])
                     :: "memory");
        __builtin_amdgcn_s_setprio(1);
        #pragma unroll
        for (int kki = 4; kki < 6; ++kki) {
            #pragma unroll
            for (int m = 0; m < 2; ++m) {
                union { i32x4 q; bf16x8 v; } u;
                u.q = hb[kki * 2 + m];
                bf16x8 a = u.v;
                acc[m][0] = __builtin_amdgcn_mfma_f32_16x16x32_bf16(a, Bf[0][kki], acc[m][0], 0, 0, 0);
                acc[m][1] = __builtin_amdgcn_mfma_f32_16x16x32_bf16(a, Bf[1][kki], acc[m][1], 0, 0, 0);
                acc[m][2] = __builtin_amdgcn_mfma_f32_16x16x32_bf16(a, Bf[2][kki], acc[m][2], 0, 0, 0);
            }
        }
        __builtin_amdgcn_s_setprio(0);
        asm volatile("s_waitcnt vmcnt(0)"
                     : "+v"(hb[12]), "+v"(hb[13]), "+v"(hb[14]), "+v"(hb[15])
                     :: "memory");
        __builtin_amdgcn_s_setprio(1);
        #pragma unroll
        for (int kki = 6; kki < 8; ++kki) {
            #pragma unroll
            for (int m = 0; m < 2; ++m) {
                union { i32x4 q; bf16x8 v; } u;
                u.q = hb[kki * 2 + m];
                bf16x8 a = u.v;
                acc[m][0] = __builtin_amdgcn_mfma_f32_16x16x32_bf16(a, Bf[0][kki], acc[m][0], 0, 0, 0);
                acc[m][1] = __builtin_amdgcn_mfma_f32_16x16x32_bf16(a, Bf[1][kki], acc[m][1], 0, 0, 0);
                acc[m][2] = __builtin_amdgcn_mfma_f32_16x16x32_bf16(a, Bf[2][kki], acc[m][2], 0, 0, 0);
            }
        }
        __builtin_amdgcn_s_setprio(0);

        // ---- SINGLE-ROUND reduce: all 8 waves write disjoint buckets ----
        #pragma unroll
        for (int m = 0; m < 2; ++m)
            #pragma unroll
            for (int nt = 0; nt < 3; ++nt)
                red[w][m][nt][lane] = acc[m][nt];
        __syncthreads();   // sync1

        // ---- SPREAD EPILOGUE (all 8 waves, one element per lane) ----
        {
            const float* redf = (const float*)red;
            float s0 = 0.f, s1 = 0.f, s2 = 0.f;
            #pragma unroll
            for (int src = 0; src < 8; ++src) {
                const int pb = (src * 2 + mE) * 3;
                s0 += redf[(pb + 0) * 256 + eoff];
                s1 += redf[(pb + 1) * 256 + eoff];
                s2 += redf[(pb + 2) * 256 + eoff];
            }
            float pr = br_ + wr0*xv0 + wr1*xv1 + wr2*xv2 + s0;
            float pz = bz_ + wz0*xv0 + wz1*xv1 + wz2*xv2 + s1;
            float rr = sigm(pr);
            float zz = sigm(pz);
            float pn = bn2_ + wn0*xv0 + wn1*xv1 + wn2*xv2 + rr * (s2 + bnn_);
            float nn = tanh_f(pn);
            float hv = nn + zz * (hst - nn);
            hst = hv;
            store_short_wt(hnext + ((long)((kkE * 4 + 2 * R + mE) * 64)
                                    + qE * 16 + 4 * (w & 3) + rE) * 8 + eEc,
                           (unsigned)f2b(hv));
            if (c == 0 && ecol == 0)
                store_dword_wt(out + t * Bn + bbase + erow, hv);
        }

        // ---- per-wave drain + LDS closer + immediate bump (R21) ----
        asm volatile("s_waitcnt vmcnt(0)" ::: "memory");  // own stores at MALL
        unsigned old = 0;
        if (lane == 0) old = atomicAdd(&lcnt, 1u);
        old = __shfl(old, 0);
        if (((old & 7u) == 7u) && lane < 16)   // 8th wave of this step
            __hip_atomic_fetch_add(&ctrl[GRP(R, lane, grp)], 1u,
                                   __ATOMIC_RELAXED, __HIP_MEMORY_SCOPE_SYSTEM);
        __syncthreads();   // sync4: red[] WAR fence (off the ring path now)
    }
}

extern "C" void kernel_launch(void* const* d_in, const int* in_sizes, int n_in,
                              void* d_out, int out_size, void* d_ws, size_t ws_size,
                              hipStream_t stream) {
    const float* inp    = (const float*)d_in[0];  // [1024][64][3]
    const float* init_h = (const float*)d_in[1];  // [64][2048]
    const float* w_ih   = (const float*)d_in[2];  // [6144][3]
    const float* w_hh   = (const float*)d_in[3];  // [6144][2048]
    const float* bias   = (const float*)d_in[4];  // [6144]
    const float* bias_n = (const float*)d_in[5];  // [2048]
    float* out = (float*)d_out;                   // [1024][64]

    unsigned short* h0 = (unsigned short*)d_ws;          // 262144 B
    unsigned short* h1 = h0 + 131072L;                   // 262144 B
    unsigned* ctrl     = (unsigned*)(h1 + 131072L);      // 32768 B

    prep_kernel<<<128, 256, 0, stream>>>(init_h, h0, ctrl);
    gru_kernel<<<NBLK, NTHR, 0, stream>>>(inp, init_h, w_ih, w_hh, bias, bias_n,
                                          h0, h1, ctrl, out);
}